// Round 11
// baseline (191.598 us; speedup 1.0000x reference)
//
#include <hip/hip_runtime.h>

// LSTM B=32768, T=50, I=2, H=32. 512 blocks x 256 threads = 4 independent
// waves/block (R9 shell: private LDS per wave, barrier-free recurrence).
// R11 KEY CHANGE: v_exp_f32 is ~50 issue-slot cycles/wave64 on gfx950
// (calibrated from R1/R7-R10: all rounds reconcile under this number; the
// kernel was exp2-throughput bound). Replace ALL 5 exp2/set with VALU-side
// polynomial exp2 (rint range-reduce + deg-5 Taylor + exponent-bit scale),
// processed as float2 set-pairs so mul/fma can lower to v_pk_fma_f32.
// Rcps stay on the (now empty) trans pipe, unbatched; activation algebra
// unfused to its VALU-minimal form.
// Core per wave: full M=16 mfma_f32_16x16x32_bf16, split-precision h
// (hh*Wh + hl*Wh + hh*Bl), h packed (lo16|hi16) u32 in private LDS,
// head = 3 MFMAs vs replicated W_out, scales folded (-log2e / +2log2e).

#define TS 50
#define HSTR 36     // u32 stride of hpk rows (144 B): 16B-aligned
#define WPB 4       // waves per block

typedef short short8 __attribute__((ext_vector_type(8)));
typedef float f32x4 __attribute__((ext_vector_type(4)));
typedef float f32x2 __attribute__((ext_vector_type(2)));

__device__ __forceinline__ float fast_rcp(float x) {
    return __builtin_amdgcn_rcpf(x);
}
// packed-friendly polynomial exp2: z in [-30, 15]
__device__ __forceinline__ f32x2 pexp2(f32x2 z) {
    f32x2 n;
    n.x = __builtin_rintf(z.x);
    n.y = __builtin_rintf(z.y);
    f32x2 f = z - n;                       // [-0.5, 0.5]
    f32x2 p = 0.0013333558f;
    p = p * f + 0.0096181291f;
    p = p * f + 0.0555041087f;
    p = p * f + 0.2402265070f;
    p = p * f + 0.6931471806f;
    p = p * f + 1.0f;                      // 2^f, rel err ~2.4e-6
    f32x2 s;
    s.x = __int_as_float(((int)n.x + 127) << 23);   // 2^n
    s.y = __int_as_float(((int)n.y + 127) << 23);
    return p * s;
}
__device__ __forceinline__ f32x2 prcp(f32x2 v) {
    f32x2 r; r.x = fast_rcp(v.x); r.y = fast_rcp(v.y); return r;
}
__device__ __forceinline__ f32x2 vmin2(f32x2 v, float s) {
    f32x2 r; r.x = fminf(v.x, s); r.y = fminf(v.y, s); return r;
}
__device__ __forceinline__ f32x2 vmax2(f32x2 v, float s) {
    f32x2 r; r.x = fmaxf(v.x, s); r.y = fmaxf(v.y, s); return r;
}
// v ~= hi + lo (bf16 each, trunc). returns (lo<<16)|hi
__device__ __forceinline__ unsigned split_pack(float v) {
    unsigned u   = __float_as_uint(v);
    float    res = v - __uint_as_float(u & 0xffff0000u);
    return __builtin_amdgcn_perm(__float_as_uint(res), u, 0x07060302u);
}
// (a & 0xffff) | (b << 16)
__device__ __forceinline__ unsigned lo_pair(unsigned a, unsigned b) {
    return __builtin_amdgcn_perm(b, a, 0x05040100u);
}
// (a >> 16) | (b & 0xffff0000)
__device__ __forceinline__ unsigned hi_pair(unsigned a, unsigned b) {
    return __builtin_amdgcn_perm(b, a, 0x07060302u);
}

union U4S8 { uint4 v; short8 s; unsigned u[4]; };

__global__ __launch_bounds__(256, 2)
void lsnn_kernel(const float* __restrict__ x,
                 const float* __restrict__ W_ih,
                 const float* __restrict__ W_hh,
                 const float* __restrict__ b_ih,
                 const float* __restrict__ b_hh,
                 const float* __restrict__ W_out,
                 const float* __restrict__ b_out,
                 const float* __restrict__ h0,
                 const float* __restrict__ c0,
                 float* __restrict__ out)
{
    // Per-wave private regions: no cross-wave sharing, no barriers.
    __shared__ __align__(16) float    x_lds[WPB][16 * 100];
    __shared__ __align__(16) unsigned hpk[WPB][16 * HSTR];
    __shared__ __align__(16) float    out_lds[WPB][16 * TS];

    const int  g_w  = threadIdx.x >> 6;
    const int  lane = threadIdx.x & 63;
    const int  u0   = lane & 15;
    const int  q    = lane >> 4;
    const long b0   = ((long)blockIdx.x * WPB + g_w) * 16;

    float*    xw = x_lds[g_w];
    unsigned* hw = hpk[g_w];
    float*    ow = out_lds[g_w];

    // ---- stage this wave's x: 1600 contiguous floats ----
    {
        const float4* xs = (const float4*)(x + b0 * 100);
        float4* xd = (float4*)xw;
        for (int i = lane; i < 400; i += 64) xd[i] = xs[i];
    }
    // ---- init packed h0 ----
    for (int i = lane; i < 512; i += 64) {
        int r = i >> 5, u = i & 31;
        hw[r * HSTR + u] = split_pack(h0[b0 * 32 + i]);
    }

    const float L2E = 1.4426950408889634f;
    const float SG  = 2.0f * L2E;

    // ---- W_hh B-tiles (8): tile n -> gate n>>1, unit-half n&1, col u0 ----
    short8 Bh[8], Bl[8];
    float  wx0[8], wx1[8], bias[8];
    #pragma unroll
    for (int n = 0; n < 8; ++n) {
        const float s = ((n >> 1) == 2) ? (2.0f * L2E) : -L2E;
        const int   gg = n * 16 + u0;
        const float* wr = W_hh + gg * 32 + q * 8;
        U4S8 uh, ul;
        #pragma unroll
        for (int p = 0; p < 4; ++p) {
            unsigned p0 = split_pack(wr[2*p]   * s);
            unsigned p1 = split_pack(wr[2*p+1] * s);
            uh.u[p] = lo_pair(p0, p1);
            ul.u[p] = hi_pair(p0, p1);
        }
        Bh[n] = uh.s;  Bl[n] = ul.s;
        wx0[n]  = W_ih[gg * 2 + 0] * s;
        wx1[n]  = W_ih[gg * 2 + 1] * s;
        bias[n] = (b_ih[gg] + b_hh[gg]) * s;
    }
    // ---- head B-frag: B[k][n] = w_out[k] replicated over n ----
    short8 Bwh, Bwl;
    {
        U4S8 uh, ul;
        #pragma unroll
        for (int p = 0; p < 4; ++p) {
            unsigned p0 = split_pack(W_out[q * 8 + 2*p]);
            unsigned p1 = split_pack(W_out[q * 8 + 2*p + 1]);
            uh.u[p] = lo_pair(p0, p1);
            ul.u[p] = hi_pair(p0, p1);
        }
        Bwh = uh.s;  Bwl = ul.s;
    }
    const float bout = b_out[0];

    // ---- c-state as pairs: cst2[r] = {c(hu=0,r), c(hu=1,r)} ----
    f32x2 cst2[4];
    #pragma unroll
    for (int r = 0; r < 4; ++r) {
        cst2[r].x = c0[(b0 + q * 4 + r) * 32 + u0];
        cst2[r].y = c0[(b0 + q * 4 + r) * 32 + 16 + u0];
    }

    const f32x4 ZV = {0.f, 0.f, 0.f, 0.f};
    const int abase = u0 * HSTR + q * 8;

    // ---- x prefetch for t=0 ----
    float2 xv[4];
    #pragma unroll
    for (int r = 0; r < 4; ++r)
        xv[r] = *(const float2*)&xw[(q * 4 + r) * 100];

    #pragma unroll 1
    for (int t = 0; t < TS; ++t) {
        // ---- A-fragment h_t: row u0, k = q*8..q*8+7 ----
        uint4 hq0 = *(const uint4*)&hw[abase];
        uint4 hq1 = *(const uint4*)&hw[abase + 4];
        U4S8 Ahh, Ahl;
        Ahh.u[0] = lo_pair(hq0.x, hq0.y); Ahh.u[1] = lo_pair(hq0.z, hq0.w);
        Ahh.u[2] = lo_pair(hq1.x, hq1.y); Ahh.u[3] = lo_pair(hq1.z, hq1.w);
        Ahl.u[0] = hi_pair(hq0.x, hq0.y); Ahl.u[1] = hi_pair(hq0.z, hq0.w);
        Ahl.u[2] = hi_pair(hq1.x, hq1.y); Ahl.u[3] = hi_pair(hq1.z, hq1.w);

        // ---- output head for h_t (skip t=0) ----
        if (t > 0) {
            f32x4 aw = ZV;
            aw = __builtin_amdgcn_mfma_f32_16x16x32_bf16(Ahh.s, Bwh, aw, 0, 0, 0);
            aw = __builtin_amdgcn_mfma_f32_16x16x32_bf16(Ahl.s, Bwh, aw, 0, 0, 0);
            aw = __builtin_amdgcn_mfma_f32_16x16x32_bf16(Ahh.s, Bwl, aw, 0, 0, 0);
            if (u0 == 0) {
                #pragma unroll
                for (int r = 0; r < 4; ++r)
                    ow[(q * 4 + r) * TS + (t - 1)] = aw[r] + bout;
            }
        }

        // ---- gates: exact fp32 C-init + 3 split-h MFMAs per tile ----
        f32x4 acc[8];
        #pragma unroll
        for (int n = 0; n < 8; ++n) {
            f32x4 ci;
            #pragma unroll
            for (int r = 0; r < 4; ++r)
                ci[r] = fmaf(wx1[n], xv[r].y, fmaf(wx0[n], xv[r].x, bias[n]));
            acc[n] = __builtin_amdgcn_mfma_f32_16x16x32_bf16(Ahh.s, Bh[n], ci,     0, 0, 0);
            acc[n] = __builtin_amdgcn_mfma_f32_16x16x32_bf16(Ahl.s, Bh[n], acc[n], 0, 0, 0);
            acc[n] = __builtin_amdgcn_mfma_f32_16x16x32_bf16(Ahh.s, Bl[n], acc[n], 0, 0, 0);
        }

        // ---- prefetch x for t+1 ----
        if (t + 1 < TS) {
            #pragma unroll
            for (int r = 0; r < 4; ++r)
                xv[r] = *(const float2*)&xw[(q * 4 + r) * 100 + 2 * (t + 1)];
        }

        // ---- activations: 4 float2 pairs (hu=0 in .x, hu=1 in .y) ----
        #pragma unroll
        for (int r = 0; r < 4; ++r) {
            f32x2 zi = {acc[0][r], acc[1][r]};              // i (scaled -log2e)
            f32x2 zf = {acc[2][r], acc[3][r]};              // f (scaled -log2e)
            f32x2 zg = vmin2((f32x2){acc[4][r], acc[5][r]}, 14.0f); // g (+2log2e)
            f32x2 zo = {acc[6][r], acc[7][r]};              // o (scaled -log2e)
            f32x2 Av = pexp2(zi);       // e^{-i}
            f32x2 Ev = pexp2(zf);       // e^{-f}
            f32x2 Bv = pexp2(zg);       // e^{2g}
            f32x2 Cv = pexp2(zo);       // e^{-o}
            f32x2 R1 = prcp((1.0f + Av) * (1.0f + Bv));
            f32x2 ig = (Bv - 1.0f) * R1;                    // sig(i)*tanh(g)
            f32x2 fv = prcp(1.0f + Ev);                     // sigmoid(f)
            f32x2 c  = fv * cst2[r] + ig;
            cst2[r] = c;
            f32x2 zc = vmax2(vmin2(c * SG, 14.0f), -24.0f);
            f32x2 Dv = pexp2(zc);       // e^{2c}
            f32x2 RQ = prcp((1.0f + Cv) * (1.0f + Dv));
            f32x2 h  = (Dv - 1.0f) * RQ;                    // sig(o)*tanh(c)
            hw[(q * 4 + r) * HSTR + u0]      = split_pack(h.x);
            hw[(q * 4 + r) * HSTR + 16 + u0] = split_pack(h.y);
        }
    }

    // ---- final head for h_50 ----
    {
        uint4 hq0 = *(const uint4*)&hw[abase];
        uint4 hq1 = *(const uint4*)&hw[abase + 4];
        U4S8 Ahh, Ahl;
        Ahh.u[0] = lo_pair(hq0.x, hq0.y); Ahh.u[1] = lo_pair(hq0.z, hq0.w);
        Ahh.u[2] = lo_pair(hq1.x, hq1.y); Ahh.u[3] = lo_pair(hq1.z, hq1.w);
        Ahl.u[0] = hi_pair(hq0.x, hq0.y); Ahl.u[1] = hi_pair(hq0.z, hq0.w);
        Ahl.u[2] = hi_pair(hq1.x, hq1.y); Ahl.u[3] = hi_pair(hq1.z, hq1.w);
        f32x4 aw = {0.f, 0.f, 0.f, 0.f};
        aw = __builtin_amdgcn_mfma_f32_16x16x32_bf16(Ahh.s, Bwh, aw, 0, 0, 0);
        aw = __builtin_amdgcn_mfma_f32_16x16x32_bf16(Ahl.s, Bwh, aw, 0, 0, 0);
        aw = __builtin_amdgcn_mfma_f32_16x16x32_bf16(Ahh.s, Bwl, aw, 0, 0, 0);
        if (u0 == 0) {
            #pragma unroll
            for (int r = 0; r < 4; ++r)
                ow[(q * 4 + r) * TS + 49] = aw[r] + bout;
        }
    }

    // ---- coalesced flush of this wave's 800 contiguous floats ----
    {
        float4* od = (float4*)(out + b0 * 50);
        const float4* os = (const float4*)ow;
        for (int i = lane; i < 200; i += 64) od[i] = os[i];
    }
}

extern "C" void kernel_launch(void* const* d_in, const int* in_sizes, int n_in,
                              void* d_out, int out_size, void* d_ws, size_t ws_size,
                              hipStream_t stream) {
    const float* x     = (const float*)d_in[0];
    const float* W_ih  = (const float*)d_in[1];
    const float* W_hh  = (const float*)d_in[2];
    const float* b_ih  = (const float*)d_in[3];
    const float* b_hh  = (const float*)d_in[4];
    const float* W_out = (const float*)d_in[5];
    const float* b_out = (const float*)d_in[6];
    const float* h0    = (const float*)d_in[7];
    const float* c0    = (const float*)d_in[8];
    float* out = (float*)d_out;

    dim3 grid(32768 / (16 * WPB)), block(64 * WPB);
    lsnn_kernel<<<grid, block, 0, stream>>>(x, W_ih, W_hh, b_ih, b_hh,
                                            W_out, b_out, h0, c0, out);
}

// Round 12
// 163.069 us; speedup vs baseline: 1.1749x; 1.1749x over previous
//
#include <hip/hip_runtime.h>

// LSTM B=32768, T=50, I=2, H=32. 512 blocks x 256 threads = 4 independent
// waves/block (R9 shell: private LDS/wave, barrier-free recurrence).
// R12: R9 program (best, 102us) with the scalar fp32 algebra re-expressed as
// f32x2 so clang emits packed fp32 (v_pk_fma/add/mul_f32, gfx90a+):
//  - activation algebra paired (hu=0,r)+(hu=1,r); exps/rcps stay SCALAR on
//    the trans pipe (R11 showed poly-exp on VALU is a loss; trans ~16cyc).
//  - C-init 64 fma -> 32 pk-fma (tile pairs).
// Issue model (calibrated R1/R7-R11): wall ~ issue/0.6; R9 issue ~1450/wave-t
// (640 exp + 128 rcp + ~380 algebra + 128 C-init + ~170 misc). pk cuts
// ~250 cyc -> predict ~85-93us.
// Core: full M=16 mfma_f32_16x16x32_bf16, split-precision h (hh*Wh+hl*Wh+hh*Bl),
// h packed (lo16|hi16) u32 in private LDS, head = 3 MFMAs vs replicated W_out,
// scales folded (-log2e / +2log2e), clamps on zg and c only (CL=14).

#define TS 50
#define HSTR 36     // u32 stride of hpk rows (144 B): 16B-aligned
#define CL 14.0f
#define WPB 4       // waves per block

typedef short short8 __attribute__((ext_vector_type(8)));
typedef float f32x4 __attribute__((ext_vector_type(4)));
typedef float f32x2 __attribute__((ext_vector_type(2)));

__device__ __forceinline__ float fast_exp2(float x) {
    return __builtin_amdgcn_exp2f(x);
}
__device__ __forceinline__ float fast_rcp(float x) {
    return __builtin_amdgcn_rcpf(x);
}
__device__ __forceinline__ f32x2 pexp(f32x2 z) {           // scalar trans x2
    f32x2 r; r.x = fast_exp2(z.x); r.y = fast_exp2(z.y); return r;
}
__device__ __forceinline__ f32x2 prcp(f32x2 v) {           // scalar trans x2
    f32x2 r; r.x = fast_rcp(v.x); r.y = fast_rcp(v.y); return r;
}
__device__ __forceinline__ f32x2 vmin2(f32x2 v, float s) { // -> v_pk_min_f32
    f32x2 r; r.x = fminf(v.x, s); r.y = fminf(v.y, s); return r;
}
// v ~= hi + lo (bf16 each, trunc). returns (lo<<16)|hi
__device__ __forceinline__ unsigned split_pack(float v) {
    unsigned u   = __float_as_uint(v);
    float    res = v - __uint_as_float(u & 0xffff0000u);
    return __builtin_amdgcn_perm(__float_as_uint(res), u, 0x07060302u);
}
// (a & 0xffff) | (b << 16)
__device__ __forceinline__ unsigned lo_pair(unsigned a, unsigned b) {
    return __builtin_amdgcn_perm(b, a, 0x05040100u);
}
// (a >> 16) | (b & 0xffff0000)
__device__ __forceinline__ unsigned hi_pair(unsigned a, unsigned b) {
    return __builtin_amdgcn_perm(b, a, 0x07060302u);
}

union U4S8 { uint4 v; short8 s; unsigned u[4]; };

__global__ __launch_bounds__(256, 2)
void lsnn_kernel(const float* __restrict__ x,
                 const float* __restrict__ W_ih,
                 const float* __restrict__ W_hh,
                 const float* __restrict__ b_ih,
                 const float* __restrict__ b_hh,
                 const float* __restrict__ W_out,
                 const float* __restrict__ b_out,
                 const float* __restrict__ h0,
                 const float* __restrict__ c0,
                 float* __restrict__ out)
{
    __shared__ __align__(16) float    x_lds[WPB][16 * 100];
    __shared__ __align__(16) unsigned hpk[WPB][16 * HSTR];
    __shared__ __align__(16) float    out_lds[WPB][16 * TS];

    const int  g_w  = threadIdx.x >> 6;
    const int  lane = threadIdx.x & 63;
    const int  u0   = lane & 15;
    const int  q    = lane >> 4;
    const long b0   = ((long)blockIdx.x * WPB + g_w) * 16;

    float*    xw = x_lds[g_w];
    unsigned* hw = hpk[g_w];
    float*    ow = out_lds[g_w];

    // ---- stage this wave's x: 1600 contiguous floats ----
    {
        const float4* xs = (const float4*)(x + b0 * 100);
        float4* xd = (float4*)xw;
        for (int i = lane; i < 400; i += 64) xd[i] = xs[i];
    }
    // ---- init packed h0 ----
    for (int i = lane; i < 512; i += 64) {
        int r = i >> 5, u = i & 31;
        hw[r * HSTR + u] = split_pack(h0[b0 * 32 + i]);
    }

    const float L2E = 1.4426950408889634f;
    const float SG  = 2.0f * L2E;

    // ---- W_hh B-tiles (8): tile n -> gate n>>1, unit-half n&1, col u0 ----
    short8 Bh[8], Bl[8];
    f32x2  wx0p[4], wx1p[4], biasp[4];   // tile pairs (2k, 2k+1)
    #pragma unroll
    for (int n = 0; n < 8; ++n) {
        const float s = ((n >> 1) == 2) ? (2.0f * L2E) : -L2E;
        const int   gg = n * 16 + u0;
        const float* wr = W_hh + gg * 32 + q * 8;
        U4S8 uh, ul;
        #pragma unroll
        for (int p = 0; p < 4; ++p) {
            unsigned p0 = split_pack(wr[2*p]   * s);
            unsigned p1 = split_pack(wr[2*p+1] * s);
            uh.u[p] = lo_pair(p0, p1);
            ul.u[p] = hi_pair(p0, p1);
        }
        Bh[n] = uh.s;  Bl[n] = ul.s;
        const int k = n >> 1, half = n & 1;
        if (half == 0) {
            wx0p[k].x  = W_ih[gg * 2 + 0] * s;
            wx1p[k].x  = W_ih[gg * 2 + 1] * s;
            biasp[k].x = (b_ih[gg] + b_hh[gg]) * s;
        } else {
            wx0p[k].y  = W_ih[gg * 2 + 0] * s;
            wx1p[k].y  = W_ih[gg * 2 + 1] * s;
            biasp[k].y = (b_ih[gg] + b_hh[gg]) * s;
        }
    }
    // ---- head B-frag: B[k][n] = w_out[k] replicated over n ----
    short8 Bwh, Bwl;
    {
        U4S8 uh, ul;
        #pragma unroll
        for (int p = 0; p < 4; ++p) {
            unsigned p0 = split_pack(W_out[q * 8 + 2*p]);
            unsigned p1 = split_pack(W_out[q * 8 + 2*p + 1]);
            uh.u[p] = lo_pair(p0, p1);
            ul.u[p] = hi_pair(p0, p1);
        }
        Bwh = uh.s;  Bwl = ul.s;
    }
    const float bout = b_out[0];

    // ---- c-state pairs: cst2[r] = {c(hu=0,r), c(hu=1,r)} ----
    f32x2 cst2[4];
    #pragma unroll
    for (int r = 0; r < 4; ++r) {
        cst2[r].x = c0[(b0 + q * 4 + r) * 32 + u0];
        cst2[r].y = c0[(b0 + q * 4 + r) * 32 + 16 + u0];
    }

    const f32x4 ZV = {0.f, 0.f, 0.f, 0.f};
    const int abase = u0 * HSTR + q * 8;

    // ---- x prefetch for t=0 ----
    float2 xv[4];
    #pragma unroll
    for (int r = 0; r < 4; ++r)
        xv[r] = *(const float2*)&xw[(q * 4 + r) * 100];

    #pragma unroll 1
    for (int t = 0; t < TS; ++t) {
        // ---- A-fragment h_t: row u0, k = q*8..q*8+7 ----
        uint4 hq0 = *(const uint4*)&hw[abase];
        uint4 hq1 = *(const uint4*)&hw[abase + 4];
        U4S8 Ahh, Ahl;
        Ahh.u[0] = lo_pair(hq0.x, hq0.y); Ahh.u[1] = lo_pair(hq0.z, hq0.w);
        Ahh.u[2] = lo_pair(hq1.x, hq1.y); Ahh.u[3] = lo_pair(hq1.z, hq1.w);
        Ahl.u[0] = hi_pair(hq0.x, hq0.y); Ahl.u[1] = hi_pair(hq0.z, hq0.w);
        Ahl.u[2] = hi_pair(hq1.x, hq1.y); Ahl.u[3] = hi_pair(hq1.z, hq1.w);

        // ---- output head for h_t (skip t=0) ----
        if (t > 0) {
            f32x4 aw = ZV;
            aw = __builtin_amdgcn_mfma_f32_16x16x32_bf16(Ahh.s, Bwh, aw, 0, 0, 0);
            aw = __builtin_amdgcn_mfma_f32_16x16x32_bf16(Ahl.s, Bwh, aw, 0, 0, 0);
            aw = __builtin_amdgcn_mfma_f32_16x16x32_bf16(Ahh.s, Bwl, aw, 0, 0, 0);
            if (u0 == 0) {
                #pragma unroll
                for (int r = 0; r < 4; ++r)
                    ow[(q * 4 + r) * TS + (t - 1)] = aw[r] + bout;
            }
        }

        // ---- C-init as pk-fma: cip[r][k] = {ci tile 2k, ci tile 2k+1} ----
        f32x2 cip[4][4];
        #pragma unroll
        for (int r = 0; r < 4; ++r) {
            #pragma unroll
            for (int k = 0; k < 4; ++k)
                cip[r][k] = wx1p[k] * xv[r].y + (wx0p[k] * xv[r].x + biasp[k]);
        }
        // ---- gates: 3 split-h MFMAs per tile ----
        f32x4 acc[8];
        #pragma unroll
        for (int n = 0; n < 8; ++n) {
            const int k = n >> 1, half = n & 1;
            f32x4 ci;
            #pragma unroll
            for (int r = 0; r < 4; ++r)
                ci[r] = half ? cip[r][k].y : cip[r][k].x;
            acc[n] = __builtin_amdgcn_mfma_f32_16x16x32_bf16(Ahh.s, Bh[n], ci,     0, 0, 0);
            acc[n] = __builtin_amdgcn_mfma_f32_16x16x32_bf16(Ahl.s, Bh[n], acc[n], 0, 0, 0);
            acc[n] = __builtin_amdgcn_mfma_f32_16x16x32_bf16(Ahh.s, Bl[n], acc[n], 0, 0, 0);
        }

        // ---- prefetch x for t+1 ----
        if (t + 1 < TS) {
            #pragma unroll
            for (int r = 0; r < 4; ++r)
                xv[r] = *(const float2*)&xw[(q * 4 + r) * 100 + 2 * (t + 1)];
        }

        // ---- activations: 4 f32x2 pairs (hu=0 -> .x, hu=1 -> .y) ----
        // gate tiles: 0,1=i; 2,3=f; 4,5=g; 6,7=o (tile index = gate*2 + hu)
        f32x2 Bv2[4], Cv2[4], P12[4], Ep2[4], PP2[4];
        #pragma unroll
        for (int r = 0; r < 4; ++r) {
            f32x2 zi = {acc[0][r], acc[1][r]};
            f32x2 zf = {acc[2][r], acc[3][r]};
            f32x2 zg = vmin2((f32x2){acc[4][r], acc[5][r]}, CL);
            f32x2 zo = {acc[6][r], acc[7][r]};
            f32x2 Av = pexp(zi);          // e^{-i}
            Bv2[r]   = pexp(zg);          // e^{2g}
            f32x2 Ev = pexp(zf);          // e^{-f}
            Cv2[r]   = pexp(zo);          // e^{-o}
            f32x2 Ap = 1.0f + Av, Bp = 1.0f + Bv2[r];
            Ep2[r] = 1.0f + Ev;
            P12[r] = Ap * Bp;
            PP2[r] = P12[r] * Ep2[r];
        }
        // batch-shared reciprocals across r-pairs (0,1) and (2,3)
        f32x2 R2[4];
        #pragma unroll
        for (int rr = 0; rr < 2; ++rr) {
            f32x2 pr = PP2[2*rr] * PP2[2*rr + 1];
            f32x2 ri = prcp(pr);
            R2[2*rr]     = PP2[2*rr + 1] * ri;
            R2[2*rr + 1] = PP2[2*rr]     * ri;
        }
        f32x2 Dv2[4], Q2[4];
        #pragma unroll
        for (int r = 0; r < 4; ++r) {
            f32x2 fv = P12[r] * R2[r];                      // sigmoid(f)
            f32x2 ig = (Bv2[r] - 1.0f) * (Ep2[r] * R2[r]);  // sig(i)*tanh(g)
            f32x2 c  = fv * cst2[r] + ig;
            cst2[r] = c;
            f32x2 zc = vmin2(c * SG, CL);
            Dv2[r] = pexp(zc);                              // e^{2c}
            Q2[r]  = (1.0f + Cv2[r]) * (1.0f + Dv2[r]);
        }
        f32x2 RQ2[4];
        #pragma unroll
        for (int rr = 0; rr < 2; ++rr) {
            f32x2 qr = Q2[2*rr] * Q2[2*rr + 1];
            f32x2 ri = prcp(qr);
            RQ2[2*rr]     = Q2[2*rr + 1] * ri;
            RQ2[2*rr + 1] = Q2[2*rr]     * ri;
        }
        #pragma unroll
        for (int r = 0; r < 4; ++r) {
            f32x2 h = (Dv2[r] - 1.0f) * RQ2[r];             // sig(o)*tanh(c)
            hw[(q * 4 + r) * HSTR + u0]      = split_pack(h.x);
            hw[(q * 4 + r) * HSTR + 16 + u0] = split_pack(h.y);
        }
    }

    // ---- final head for h_50 ----
    {
        uint4 hq0 = *(const uint4*)&hw[abase];
        uint4 hq1 = *(const uint4*)&hw[abase + 4];
        U4S8 Ahh, Ahl;
        Ahh.u[0] = lo_pair(hq0.x, hq0.y); Ahh.u[1] = lo_pair(hq0.z, hq0.w);
        Ahh.u[2] = lo_pair(hq1.x, hq1.y); Ahh.u[3] = lo_pair(hq1.z, hq1.w);
        Ahl.u[0] = hi_pair(hq0.x, hq0.y); Ahl.u[1] = hi_pair(hq0.z, hq0.w);
        Ahl.u[2] = hi_pair(hq1.x, hq1.y); Ahl.u[3] = hi_pair(hq1.z, hq1.w);
        f32x4 aw = {0.f, 0.f, 0.f, 0.f};
        aw = __builtin_amdgcn_mfma_f32_16x16x32_bf16(Ahh.s, Bwh, aw, 0, 0, 0);
        aw = __builtin_amdgcn_mfma_f32_16x16x32_bf16(Ahl.s, Bwh, aw, 0, 0, 0);
        aw = __builtin_amdgcn_mfma_f32_16x16x32_bf16(Ahh.s, Bwl, aw, 0, 0, 0);
        if (u0 == 0) {
            #pragma unroll
            for (int r = 0; r < 4; ++r)
                ow[(q * 4 + r) * TS + 49] = aw[r] + bout;
        }
    }

    // ---- coalesced flush of this wave's 800 contiguous floats ----
    {
        float4* od = (float4*)(out + b0 * 50);
        const float4* os = (const float4*)ow;
        for (int i = lane; i < 200; i += 64) od[i] = os[i];
    }
}

extern "C" void kernel_launch(void* const* d_in, const int* in_sizes, int n_in,
                              void* d_out, int out_size, void* d_ws, size_t ws_size,
                              hipStream_t stream) {
    const float* x     = (const float*)d_in[0];
    const float* W_ih  = (const float*)d_in[1];
    const float* W_hh  = (const float*)d_in[2];
    const float* b_ih  = (const float*)d_in[3];
    const float* b_hh  = (const float*)d_in[4];
    const float* W_out = (const float*)d_in[5];
    const float* b_out = (const float*)d_in[6];
    const float* h0    = (const float*)d_in[7];
    const float* c0    = (const float*)d_in[8];
    float* out = (float*)d_out;

    dim3 grid(32768 / (16 * WPB)), block(64 * WPB);
    lsnn_kernel<<<grid, block, 0, stream>>>(x, W_ih, W_hh, b_ih, b_hh,
                                            W_out, b_out, h0, c0, out);
}